// Round 1
// baseline (405.203 us; speedup 1.0000x reference)
//
#include <hip/hip_runtime.h>

#define IN_F 128
#define C1 64
#define NG 128
#define CAT 192

// ---------------- CSR build ----------------

__global__ void zero2_k(int* __restrict__ a, int* __restrict__ b, int n) {
  int i = blockIdx.x * blockDim.x + threadIdx.x;
  if (i < n) { a[i] = 0; b[i] = 0; }
}

__global__ void count_k(const int* __restrict__ dst, int* __restrict__ counts, int e) {
  int i = blockIdx.x * blockDim.x + threadIdx.x;
  if (i < e) atomicAdd(&counts[dst[i]], 1);
}

__global__ void scan1_k(const int* __restrict__ counts, int* __restrict__ rowptr,
                        int* __restrict__ bsums, int n) {
  __shared__ int lds[256];
  int t = threadIdx.x;
  int base = blockIdx.x * 1024 + t * 4;
  int v0 = 0, v1 = 0, v2 = 0, v3 = 0;
  if (base + 3 < n) {
    const int4 c = *(const int4*)(counts + base);
    v0 = c.x; v1 = c.y; v2 = c.z; v3 = c.w;
  } else {
    if (base     < n) v0 = counts[base];
    if (base + 1 < n) v1 = counts[base + 1];
    if (base + 2 < n) v2 = counts[base + 2];
    if (base + 3 < n) v3 = counts[base + 3];
  }
  int s = v0 + v1 + v2 + v3;
  lds[t] = s;
  __syncthreads();
  #pragma unroll
  for (int off = 1; off < 256; off <<= 1) {
    int x = lds[t] + ((t >= off) ? lds[t - off] : 0);
    __syncthreads();
    lds[t] = x;
    __syncthreads();
  }
  int excl = lds[t] - s;
  if (base     < n) rowptr[base]     = excl;
  if (base + 1 < n) rowptr[base + 1] = excl + v0;
  if (base + 2 < n) rowptr[base + 2] = excl + v0 + v1;
  if (base + 3 < n) rowptr[base + 3] = excl + v0 + v1 + v2;
  if (t == 255) bsums[blockIdx.x] = lds[255];
}

__global__ void scan2_k(const int* __restrict__ bsums, int* __restrict__ boff, int nb) {
  __shared__ int lds[256];
  int t = threadIdx.x;
  int v = (t < nb) ? bsums[t] : 0;
  lds[t] = v;
  __syncthreads();
  #pragma unroll
  for (int off = 1; off < 256; off <<= 1) {
    int x = lds[t] + ((t >= off) ? lds[t - off] : 0);
    __syncthreads();
    lds[t] = x;
    __syncthreads();
  }
  if (t < nb) boff[t] = lds[t] - v;
}

__global__ void scan3_k(int* __restrict__ rowptr, const int* __restrict__ boff,
                        const int* __restrict__ counts, float* __restrict__ dinv, int n) {
  int i = blockIdx.x * blockDim.x + threadIdx.x;
  if (i < n) {
    rowptr[i] += boff[i >> 10];
    dinv[i] = rsqrtf((float)counts[i] + 1.0f);  // +1 = self loop
  }
}

__global__ void fill_k(const int* __restrict__ src, const int* __restrict__ dst,
                       int* __restrict__ cursor, const int* __restrict__ rowptr,
                       int* __restrict__ csr, int e) {
  int i = blockIdx.x * blockDim.x + threadIdx.x;
  if (i < e) {
    int d = dst[i];
    int p = atomicAdd(&cursor[d], 1);
    csr[rowptr[d] + p] = src[i];
  }
}

// ---------------- dense GEMM  Y[N,64] = X[N,K] @ W[K,64] ----------------
// 64 rows x 64 cols per block, 4x4 micro-tile per thread, BK=32.

template <int K>
__global__ __launch_bounds__(256) void gemm_k(const float* __restrict__ X,
                                              const float* __restrict__ W,
                                              float* __restrict__ Y, int n) {
  __shared__ float XT[32][68];  // transposed X chunk, padded stride (272B, 16B-aligned)
  __shared__ float Ws[32][64];
  int t = threadIdx.x;
  int row0 = blockIdx.x * 64;
  int tx = t & 15, ty = t >> 4;
  float acc[4][4] = {};
  for (int kt = 0; kt < K; kt += 32) {
    {  // stage X^T: 64 rows x 32 k
      int r = t >> 2;   // 0..63
      int q = t & 3;    // 0..3
      int gr = row0 + r;
      #pragma unroll
      for (int h = 0; h < 2; h++) {
        int k0 = q * 8 + h * 4;
        float4 xv = make_float4(0.f, 0.f, 0.f, 0.f);
        if (gr < n) xv = *(const float4*)(X + (size_t)gr * K + kt + k0);
        XT[k0 + 0][r] = xv.x;
        XT[k0 + 1][r] = xv.y;
        XT[k0 + 2][r] = xv.z;
        XT[k0 + 3][r] = xv.w;
      }
    }
    {  // stage W: 32 k x 64 cols
      int k = t >> 3;   // 0..31
      int q = t & 7;    // 0..7
      *(float4*)&Ws[k][q * 8 + 0] = *(const float4*)(W + (size_t)(kt + k) * 64 + q * 8);
      *(float4*)&Ws[k][q * 8 + 4] = *(const float4*)(W + (size_t)(kt + k) * 64 + q * 8 + 4);
    }
    __syncthreads();
    #pragma unroll
    for (int k = 0; k < 32; k++) {
      float4 xv = *(const float4*)&XT[k][ty * 4];
      float4 wv = *(const float4*)&Ws[k][tx * 4];
      float xa[4] = {xv.x, xv.y, xv.z, xv.w};
      float wa[4] = {wv.x, wv.y, wv.z, wv.w};
      #pragma unroll
      for (int i = 0; i < 4; i++)
        #pragma unroll
        for (int j = 0; j < 4; j++)
          acc[i][j] += xa[i] * wa[j];
    }
    __syncthreads();
  }
  #pragma unroll
  for (int i = 0; i < 4; i++) {
    int gr = row0 + ty * 4 + i;
    if (gr < n) {
      float4 o = make_float4(acc[i][0], acc[i][1], acc[i][2], acc[i][3]);
      *(float4*)(Y + (size_t)gr * 64 + tx * 4) = o;
    }
  }
}

// ---------------- edge aggregation (gather over CSR) + bias + relu ----------------
// 16 threads per node (float4 each over 64 feats).

__global__ __launch_bounds__(256) void gather_k(const float* __restrict__ xw,
                                                float* __restrict__ hout,
                                                const int* __restrict__ rowptr,
                                                const int* __restrict__ counts,
                                                const int* __restrict__ csr,
                                                const float* __restrict__ dinv,
                                                const float* __restrict__ bias, int n) {
  int idx = blockIdx.x * 256 + threadIdx.x;
  int nid = idx >> 4;
  int lane = idx & 15;
  if (nid >= n) return;
  float di = dinv[nid];
  float4 a = *(const float4*)(xw + (size_t)nid * 64 + lane * 4);
  float sc = di * di;  // self-loop norm
  float ax = a.x * sc, ay = a.y * sc, az = a.z * sc, aw = a.w * sc;
  int st = rowptr[nid];
  int cn = counts[nid];
  for (int i = 0; i < cn; i++) {
    int s = csr[st + i];
    float wgt = dinv[s] * di;
    float4 xs = *(const float4*)(xw + (size_t)s * 64 + lane * 4);
    ax += xs.x * wgt; ay += xs.y * wgt; az += xs.z * wgt; aw += xs.w * wgt;
  }
  float4 b = *(const float4*)(bias + lane * 4);
  ax = fmaxf(ax + b.x, 0.f);
  ay = fmaxf(ay + b.y, 0.f);
  az = fmaxf(az + b.z, 0.f);
  aw = fmaxf(aw + b.w, 0.f);
  *(float4*)(hout + (size_t)nid * 64 + lane * 4) = make_float4(ax, ay, az, aw);
}

// ---------------- pooling ----------------

__global__ void bounds_k(const int* __restrict__ batch, int* __restrict__ startg, int n) {
  int t = threadIdx.x;
  if (t <= NG) {
    int lo = 0, hi = n;
    while (lo < hi) {
      int mid = (lo + hi) >> 1;
      if (batch[mid] < t) lo = mid + 1; else hi = mid;
    }
    startg[t] = lo;
  }
}

__global__ __launch_bounds__(1024) void pool_k(const float* __restrict__ h,
                                               const int* __restrict__ startg,
                                               float* __restrict__ xcat) {
  int g = blockIdx.x;
  int s = startg[g], e = startg[g + 1];
  int lane = threadIdx.x & 63;
  int wv = threadIdx.x >> 6;  // 0..15
  float sum = 0.f, mx = 0.f;  // relu output >= 0, so 0-init max matches ref semantics
  for (int nn = s + wv; nn < e; nn += 16) {
    float v = h[(size_t)nn * 64 + lane];
    sum += v;
    mx = fmaxf(mx, v);
  }
  __shared__ float lsum[16][64];
  __shared__ float lmax[16][64];
  lsum[wv][lane] = sum;
  lmax[wv][lane] = mx;
  __syncthreads();
  if (wv == 0) {
    #pragma unroll
    for (int i = 1; i < 16; i++) {
      sum += lsum[i][lane];
      mx = fmaxf(mx, lmax[i][lane]);
    }
    int cnt = e - s;
    xcat[g * CAT + lane]        = sum;
    xcat[g * CAT + 64 + lane]   = sum / fmaxf((float)cnt, 1.0f);
    xcat[g * CAT + 128 + lane]  = mx;
  }
}

__global__ void head_k(const float* __restrict__ xcat, const float* __restrict__ Wlin,
                       const float* __restrict__ blin, float* __restrict__ out) {
  int t = threadIdx.x;  // 256 = 128 graphs x 2 outputs
  int g = t >> 1, o = t & 1;
  float acc = blin[o];
  #pragma unroll 8
  for (int k = 0; k < CAT; k++) acc += xcat[g * CAT + k] * Wlin[k * 2 + o];
  out[g * 2 + o] = acc;
}

// ---------------- launch ----------------

extern "C" void kernel_launch(void* const* d_in, const int* in_sizes, int n_in,
                              void* d_out, int out_size, void* d_ws, size_t ws_size,
                              hipStream_t stream) {
  const float* x    = (const float*)d_in[0];
  const float* W1   = (const float*)d_in[1];
  const float* b1   = (const float*)d_in[2];
  const float* W2   = (const float*)d_in[3];
  const float* b2   = (const float*)d_in[4];
  const float* Wlin = (const float*)d_in[5];
  const float* blin = (const float*)d_in[6];
  const int*   ei   = (const int*)d_in[7];
  const int*   batch= (const int*)d_in[8];

  const int N = in_sizes[0] / IN_F;      // 100000
  const int E = in_sizes[7] / 2;         // 1600000
  const int* src = ei;
  const int* dst = ei + E;

  char* w = (char*)d_ws;
  auto alloc = [&](size_t bytes) {
    void* p = (void*)w;
    w += (bytes + 255) & ~(size_t)255;
    return p;
  };
  int*   counts = (int*)alloc((size_t)N * 4);
  int*   cursor = (int*)alloc((size_t)N * 4);
  int*   rowptr = (int*)alloc((size_t)N * 4);
  int*   bsums  = (int*)alloc(256 * 4);
  int*   boff   = (int*)alloc(256 * 4);
  int*   csr    = (int*)alloc((size_t)E * 4);
  float* dinv   = (float*)alloc((size_t)N * 4);
  int*   startg = (int*)alloc((NG + 2) * 4);
  float* bufA   = (float*)alloc((size_t)N * 64 * 4);
  float* bufB   = (float*)alloc((size_t)N * 64 * 4);

  float* xcat = (float*)d_out;               // [128][192]
  float* outh = (float*)d_out + NG * CAT;    // [128][2]

  int nb = (N + 1023) / 1024;                // 98, fits scan2's 256 capacity

  zero2_k <<<(N + 255) / 256, 256, 0, stream>>>(counts, cursor, N);
  count_k <<<(E + 255) / 256, 256, 0, stream>>>(dst, counts, E);
  scan1_k <<<nb, 256, 0, stream>>>(counts, rowptr, bsums, N);
  scan2_k <<<1, 256, 0, stream>>>(bsums, boff, nb);
  scan3_k <<<(N + 255) / 256, 256, 0, stream>>>(rowptr, boff, counts, dinv, N);
  fill_k  <<<(E + 255) / 256, 256, 0, stream>>>(src, dst, cursor, rowptr, csr, E);

  // layer 1: xw = x @ W1 ; h1 = relu(aggregate + b1)
  gemm_k<IN_F> <<<(N + 63) / 64, 256, 0, stream>>>(x, W1, bufA, N);
  gather_k <<<(N * 16 + 255) / 256, 256, 0, stream>>>(bufA, bufB, rowptr, counts, csr, dinv, b1, N);

  // layer 2: xw2 = h1 @ W2 ; h2 = relu(aggregate + b2)
  gemm_k<C1> <<<(N + 63) / 64, 256, 0, stream>>>(bufB, W2, bufA, N);
  gather_k <<<(N * 16 + 255) / 256, 256, 0, stream>>>(bufA, bufB, rowptr, counts, csr, dinv, b2, N);

  // pooling + head
  bounds_k <<<1, 256, 0, stream>>>(batch, startg, N);
  pool_k <<<NG, 1024, 0, stream>>>(bufB, startg, xcat);
  head_k <<<1, 256, 0, stream>>>(xcat, Wlin, blin, outh);
}

// Round 2
// 282.003 us; speedup vs baseline: 1.4369x; 1.4369x over previous
//
#include <hip/hip_runtime.h>

#define IN_F 128
#define C1 64
#define NG 128
#define CAT 192

// ================= CSR build (locality-clean, near-atomic-free) =================
// digit = dst >> 9  (512 nodes per digit)

__global__ __launch_bounds__(256) void hist_k(const int* __restrict__ dst, int e,
                                              int* __restrict__ ghist, int ndig) {
  __shared__ int h[256];
  int t = threadIdx.x;
  h[t] = 0;
  __syncthreads();
  int base = blockIdx.x * 4096;
  #pragma unroll
  for (int i = 0; i < 16; i++) {
    int j = base + t + i * 256;
    if (j < e) atomicAdd(&h[dst[j] >> 9], 1);
  }
  __syncthreads();
  if (t < ndig && h[t] > 0) atomicAdd(&ghist[t], h[t]);
}

__global__ void dscan_k(const int* __restrict__ ghist, int* __restrict__ dstart,
                        int* __restrict__ gcur, int ndig, int e) {
  __shared__ int lds[256];
  int t = threadIdx.x;
  int v = (t < ndig) ? ghist[t] : 0;
  lds[t] = v;
  __syncthreads();
  #pragma unroll
  for (int off = 1; off < 256; off <<= 1) {
    int x = lds[t] + ((t >= off) ? lds[t - off] : 0);
    __syncthreads();
    lds[t] = x;
    __syncthreads();
  }
  int excl = lds[t] - v;
  if (t < ndig) { dstart[t] = excl; gcur[t] = excl; }
  if (t == 0) dstart[ndig] = e;
}

// stage (src,dst) pairs grouped by digit; per-block claim -> contiguous runs.
__global__ __launch_bounds__(256) void stage_k(const int* __restrict__ src,
                                               const int* __restrict__ dst, int e,
                                               int* __restrict__ gcur,
                                               int2* __restrict__ stage, int ndig) {
  __shared__ int h[256];    // local digit counts, then global base per digit
  __shared__ int cur[256];  // local rank cursors
  int t = threadIdx.x;
  h[t] = 0;
  __syncthreads();
  int base = blockIdx.x * 4096;
  int mys[16], myd[16];
  #pragma unroll
  for (int i = 0; i < 16; i++) {
    int j = base + t + i * 256;
    if (j < e) {
      mys[i] = src[j];
      myd[i] = dst[j];
      atomicAdd(&h[myd[i] >> 9], 1);
    } else {
      myd[i] = -1;
    }
  }
  __syncthreads();
  int cnt = h[t];
  __syncthreads();
  int gbase = 0;
  if (t < ndig && cnt > 0) gbase = atomicAdd(&gcur[t], cnt);
  h[t] = gbase;
  cur[t] = 0;
  __syncthreads();
  #pragma unroll
  for (int i = 0; i < 16; i++) {
    if (myd[i] >= 0) {
      int d = myd[i] >> 9;
      int r = atomicAdd(&cur[d], 1);
      stage[h[d] + r] = make_int2(mys[i], myd[i]);
    }
  }
}

// one block per digit: build rowptr/counts/dinv + scatter src into its own 32KB csr window.
__global__ __launch_bounds__(256) void csr_k(const int2* __restrict__ stage,
                                             const int* __restrict__ dstart,
                                             int* __restrict__ rowptr,
                                             int* __restrict__ counts,
                                             float* __restrict__ dinv,
                                             int* __restrict__ csr, int n) {
  __shared__ int hc[512];
  __shared__ int hb[512];
  __shared__ int cu[512];
  __shared__ int sc[256];
  int dg = blockIdx.x;
  int t = threadIdx.x;
  int n0 = dg * 512;
  int nloc = min(n - n0, 512);
  int e0 = dstart[dg], e1 = dstart[dg + 1];
  hc[t] = 0; hc[t + 256] = 0;
  __syncthreads();
  for (int j = e0 + t; j < e1; j += 256) atomicAdd(&hc[stage[j].y - n0], 1);
  __syncthreads();
  // exclusive scan of hc[0..511]
  int a0 = hc[2 * t], a1 = hc[2 * t + 1];
  int s = a0 + a1;
  sc[t] = s;
  __syncthreads();
  #pragma unroll
  for (int off = 1; off < 256; off <<= 1) {
    int x = sc[t] + ((t >= off) ? sc[t - off] : 0);
    __syncthreads();
    sc[t] = x;
    __syncthreads();
  }
  int excl = sc[t] - s;
  hb[2 * t] = excl;
  hb[2 * t + 1] = excl + a0;
  cu[2 * t] = 0; cu[2 * t + 1] = 0;
  __syncthreads();
  for (int i = t; i < nloc; i += 256) {
    int node = n0 + i;
    rowptr[node] = e0 + hb[i];
    counts[node] = hc[i];
    dinv[node] = rsqrtf((float)hc[i] + 1.0f);  // +1 self loop
  }
  __syncthreads();
  for (int j = e0 + t; j < e1; j += 256) {
    int2 p = stage[j];
    int li = p.y - n0;
    int r = atomicAdd(&cu[li], 1);
    csr[e0 + hb[li] + r] = p.x;
  }
}

// ================= dense GEMM  Y[N,64] = X[N,K] @ W[K,64] =================

template <int K>
__global__ __launch_bounds__(256) void gemm_k(const float* __restrict__ X,
                                              const float* __restrict__ W,
                                              float* __restrict__ Y, int n) {
  __shared__ float XT[32][68];
  __shared__ float Ws[32][64];
  int t = threadIdx.x;
  int row0 = blockIdx.x * 64;
  int tx = t & 15, ty = t >> 4;
  float acc[4][4] = {};
  for (int kt = 0; kt < K; kt += 32) {
    {
      int r = t >> 2;
      int q = t & 3;
      int gr = row0 + r;
      #pragma unroll
      for (int h = 0; h < 2; h++) {
        int k0 = q * 8 + h * 4;
        float4 xv = make_float4(0.f, 0.f, 0.f, 0.f);
        if (gr < n) xv = *(const float4*)(X + (size_t)gr * K + kt + k0);
        XT[k0 + 0][r] = xv.x;
        XT[k0 + 1][r] = xv.y;
        XT[k0 + 2][r] = xv.z;
        XT[k0 + 3][r] = xv.w;
      }
    }
    {
      int k = t >> 3;
      int q = t & 7;
      *(float4*)&Ws[k][q * 8 + 0] = *(const float4*)(W + (size_t)(kt + k) * 64 + q * 8);
      *(float4*)&Ws[k][q * 8 + 4] = *(const float4*)(W + (size_t)(kt + k) * 64 + q * 8 + 4);
    }
    __syncthreads();
    #pragma unroll
    for (int k = 0; k < 32; k++) {
      float4 xv = *(const float4*)&XT[k][ty * 4];
      float4 wv = *(const float4*)&Ws[k][tx * 4];
      float xa[4] = {xv.x, xv.y, xv.z, xv.w};
      float wa[4] = {wv.x, wv.y, wv.z, wv.w};
      #pragma unroll
      for (int i = 0; i < 4; i++)
        #pragma unroll
        for (int j = 0; j < 4; j++)
          acc[i][j] += xa[i] * wa[j];
    }
    __syncthreads();
  }
  #pragma unroll
  for (int i = 0; i < 4; i++) {
    int gr = row0 + ty * 4 + i;
    if (gr < n) {
      float4 o = make_float4(acc[i][0], acc[i][1], acc[i][2], acc[i][3]);
      *(float4*)(Y + (size_t)gr * 64 + tx * 4) = o;
    }
  }
}

// ================= edge aggregation (gather) + bias + relu =================

__global__ __launch_bounds__(256) void gather_k(const float* __restrict__ xw,
                                                float* __restrict__ hout,
                                                const int* __restrict__ rowptr,
                                                const int* __restrict__ counts,
                                                const int* __restrict__ csr,
                                                const float* __restrict__ dinv,
                                                const float* __restrict__ bias, int n) {
  int idx = blockIdx.x * 256 + threadIdx.x;
  int nid = idx >> 4;
  int lane = idx & 15;
  if (nid >= n) return;
  float di = dinv[nid];
  float4 a = *(const float4*)(xw + (size_t)nid * 64 + lane * 4);
  float sc = di * di;
  float ax = a.x * sc, ay = a.y * sc, az = a.z * sc, aw = a.w * sc;
  int st = rowptr[nid];
  int cn = counts[nid];
  for (int i = 0; i < cn; i++) {
    int s = csr[st + i];
    float wgt = dinv[s] * di;
    float4 xs = *(const float4*)(xw + (size_t)s * 64 + lane * 4);
    ax += xs.x * wgt; ay += xs.y * wgt; az += xs.z * wgt; aw += xs.w * wgt;
  }
  float4 b = *(const float4*)(bias + lane * 4);
  ax = fmaxf(ax + b.x, 0.f);
  ay = fmaxf(ay + b.y, 0.f);
  az = fmaxf(az + b.z, 0.f);
  aw = fmaxf(aw + b.w, 0.f);
  *(float4*)(hout + (size_t)nid * 64 + lane * 4) = make_float4(ax, ay, az, aw);
}

// ================= pooling + head =================

__global__ void bounds_k(const int* __restrict__ batch, int* __restrict__ startg, int n) {
  int t = threadIdx.x;
  if (t <= NG) {
    int lo = 0, hi = n;
    while (lo < hi) {
      int mid = (lo + hi) >> 1;
      if (batch[mid] < t) lo = mid + 1; else hi = mid;
    }
    startg[t] = lo;
  }
}

__global__ __launch_bounds__(1024) void pool_k(const float* __restrict__ h,
                                               const int* __restrict__ startg,
                                               float* __restrict__ xcat) {
  int g = blockIdx.x;
  int s = startg[g], e = startg[g + 1];
  int lane = threadIdx.x & 63;
  int wv = threadIdx.x >> 6;
  float sum = 0.f, mx = 0.f;
  for (int nn = s + wv; nn < e; nn += 16) {
    float v = h[(size_t)nn * 64 + lane];
    sum += v;
    mx = fmaxf(mx, v);
  }
  __shared__ float lsum[16][64];
  __shared__ float lmax[16][64];
  lsum[wv][lane] = sum;
  lmax[wv][lane] = mx;
  __syncthreads();
  if (wv == 0) {
    #pragma unroll
    for (int i = 1; i < 16; i++) {
      sum += lsum[i][lane];
      mx = fmaxf(mx, lmax[i][lane]);
    }
    int cnt = e - s;
    xcat[g * CAT + lane]       = sum;
    xcat[g * CAT + 64 + lane]  = sum / fmaxf((float)cnt, 1.0f);
    xcat[g * CAT + 128 + lane] = mx;
  }
}

__global__ void head_k(const float* __restrict__ xcat, const float* __restrict__ Wlin,
                       const float* __restrict__ blin, float* __restrict__ out) {
  int t = threadIdx.x;
  int g = t >> 1, o = t & 1;
  float acc = blin[o];
  #pragma unroll 8
  for (int k = 0; k < CAT; k++) acc += xcat[g * CAT + k] * Wlin[k * 2 + o];
  out[g * 2 + o] = acc;
}

// ================= launch =================

extern "C" void kernel_launch(void* const* d_in, const int* in_sizes, int n_in,
                              void* d_out, int out_size, void* d_ws, size_t ws_size,
                              hipStream_t stream) {
  const float* x    = (const float*)d_in[0];
  const float* W1   = (const float*)d_in[1];
  const float* b1   = (const float*)d_in[2];
  const float* W2   = (const float*)d_in[3];
  const float* b2   = (const float*)d_in[4];
  const float* Wlin = (const float*)d_in[5];
  const float* blin = (const float*)d_in[6];
  const int*   ei   = (const int*)d_in[7];
  const int*   batch= (const int*)d_in[8];

  const int N = in_sizes[0] / IN_F;      // 100000
  const int E = in_sizes[7] / 2;         // 1600000
  const int* src = ei;
  const int* dst = ei + E;
  const int ndig = (N + 511) >> 9;       // 196
  const int nbE  = (E + 4095) / 4096;    // 391

  char* w = (char*)d_ws;
  auto alloc = [&](size_t bytes) {
    void* p = (void*)w;
    w += (bytes + 255) & ~(size_t)255;
    return p;
  };
  int*   rowptr = (int*)alloc((size_t)N * 4);
  int*   counts = (int*)alloc((size_t)N * 4);
  float* dinv   = (float*)alloc((size_t)N * 4);
  int*   csr    = (int*)alloc((size_t)E * 4);
  int*   ghist  = (int*)alloc(256 * 4);
  int*   dstart = (int*)alloc(260 * 4);
  int*   gcur   = (int*)alloc(256 * 4);
  int*   startg = (int*)alloc((NG + 2) * 4);
  float* bufA   = (float*)alloc((size_t)N * 64 * 4);
  float* bufB   = (float*)alloc((size_t)N * 64 * 4);
  int2*  stage  = (int2*)bufA;  // alias: stage dead before gemm1 writes bufA

  float* xcat = (float*)d_out;
  float* outh = (float*)d_out + NG * CAT;

  hipMemsetAsync(ghist, 0, 256 * 4, stream);
  hist_k  <<<nbE, 256, 0, stream>>>(dst, E, ghist, ndig);
  dscan_k <<<1, 256, 0, stream>>>(ghist, dstart, gcur, ndig, E);
  stage_k <<<nbE, 256, 0, stream>>>(src, dst, E, gcur, stage, ndig);
  csr_k   <<<ndig, 256, 0, stream>>>(stage, dstart, rowptr, counts, dinv, csr, N);

  // layer 1
  gemm_k<IN_F> <<<(N + 63) / 64, 256, 0, stream>>>(x, W1, bufA, N);
  gather_k <<<(N * 16 + 255) / 256, 256, 0, stream>>>(bufA, bufB, rowptr, counts, csr, dinv, b1, N);

  // layer 2
  gemm_k<C1> <<<(N + 63) / 64, 256, 0, stream>>>(bufB, W2, bufA, N);
  gather_k <<<(N * 16 + 255) / 256, 256, 0, stream>>>(bufA, bufB, rowptr, counts, csr, dinv, b2, N);

  // pooling + head
  bounds_k <<<1, 256, 0, stream>>>(batch, startg, N);
  pool_k <<<NG, 1024, 0, stream>>>(bufB, startg, xcat);
  head_k <<<1, 256, 0, stream>>>(xcat, Wlin, blin, outh);
}